// Round 1
// baseline (1569.544 us; speedup 1.0000x reference)
//
#include <hip/hip_runtime.h>

// Problem constants
#define B_    8
#define CIN   64
#define T_    12
#define N_    4096
#define KS_   3
#define COUT  64
#define P_    (B_*COUT*T_)      // 6144 rows of the big GEMM
#define GSZ   ((size_t)N_*N_)   // per-k basis matrix elements
#define WSZ   ((size_t)P_*N_)   // per-k W elements

typedef __attribute__((ext_vector_type(8))) short bf16x8;
typedef __attribute__((ext_vector_type(4))) float f32x4;

__device__ __forceinline__ unsigned short f2bf(float f) {
  unsigned int u = __float_as_uint(f);
  u += 0x7FFF + ((u >> 16) & 1);   // RNE
  return (unsigned short)(u >> 16);
}

__device__ __forceinline__ void async16(unsigned short* lds, const unsigned short* g) {
  __builtin_amdgcn_global_load_lds(
      (const __attribute__((address_space(1))) unsigned int*)g,
      (__attribute__((address_space(3))) unsigned int*)lds, 16, 0, 0);
}

// ---------------- Kernel 1: cast graph_basis fp32 -> bf16 (same layout [k][n][m]) ----------------
__global__ __launch_bounds__(256) void cast_g(const float4* __restrict__ in,
                                              ushort4* __restrict__ out) {
  int i = blockIdx.x * 256 + threadIdx.x;   // exact: 3*4096*4096/4 threads
  float4 v = in[i];
  ushort4 o;
  o.x = f2bf(v.x); o.y = f2bf(v.y); o.z = f2bf(v.z); o.w = f2bf(v.w);
  out[i] = o;
}

// ---------------- Kernel 2: W[k][p][m] = sum_i theta[i,o,k] * x[b,i,t,m], p=(b*64+o)*12+t ----------
__global__ __launch_bounds__(256) void stage1(const float* __restrict__ x,
                                              const float* __restrict__ theta,
                                              unsigned short* __restrict__ Wt) {
  __shared__ float sTh[CIN*COUT*KS_];   // 48 KB
  for (int idx = threadIdx.x; idx < CIN*COUT*KS_; idx += 256) sTh[idx] = theta[idx];
  __syncthreads();

  int bid = blockIdx.x;       // 96 (b,t) * 16 m-chunks
  int mc  = bid & 15;
  int bt  = bid >> 4;
  int b   = bt / T_;
  int t   = bt - b * T_;
  int m   = mc * 256 + threadIdx.x;

  const float* xp = x + ((size_t)(b * CIN) * T_ + t) * N_ + m;
  float xi[CIN];
#pragma unroll
  for (int i = 0; i < CIN; ++i) xi[i] = xp[(size_t)i * T_ * N_];

  size_t ob = ((size_t)(b * COUT) * T_ + t) * N_ + m;   // p for o=0
  for (int o = 0; o < COUT; ++o) {
    float a0 = 0.f, a1 = 0.f, a2 = 0.f;
#pragma unroll
    for (int i = 0; i < CIN; ++i) {
      float xv = xi[i];
      a0 = fmaf(xv, sTh[(i * COUT + o) * 3 + 0], a0);
      a1 = fmaf(xv, sTh[(i * COUT + o) * 3 + 1], a1);
      a2 = fmaf(xv, sTh[(i * COUT + o) * 3 + 2], a2);
    }
    size_t pm = ob + (size_t)o * T_ * N_;
    Wt[pm]            = f2bf(a0);
    Wt[WSZ + pm]      = f2bf(a1);
    Wt[2 * WSZ + pm]  = f2bf(a2);
  }
}

// ---------------- Kernel 3: C[p,n] = sum_k sum_m W[k,p,m]*G[k,n,m]; fused bias+residual+relu ------
#define BM 128
#define BN 128
#define BK 32

__global__ __launch_bounds__(256) void gemm_fused(const unsigned short* __restrict__ Wt,
                                                  const unsigned short* __restrict__ Gb,
                                                  const float* __restrict__ xres,
                                                  const float* __restrict__ bias,
                                                  float* __restrict__ out) {
  __shared__ unsigned short sA[BM * BK];   // [row][32] bf16, 8 KB
  __shared__ unsigned short sB[BN * BK];

  int tid = threadIdx.x;
  int l = tid & 63, w = tid >> 6;

  // XCD-aware swizzle: nwg = 1536 = 8 * 192 (bijective)
  int bid = blockIdx.x;
  int swz = (bid & 7) * 192 + (bid >> 3);
  int pm = swz >> 5;          // M tiles: 48
  int pn = swz & 31;          // N tiles: 32
  int p0 = pm * BM, n0 = pn * BN;
  int wr = w >> 1, wc = w & 1;

  // staging addressing: wave w, issue j covers rows [w*16 + j*64, +16), 16B per lane
  int srow = w * 16 + (l >> 2);
  int scol = (l & 3) * 8;
  unsigned short* ldsA0 = &sA[w * 512];
  unsigned short* ldsA1 = &sA[w * 512 + 2048];
  unsigned short* ldsB0 = &sB[w * 512];
  unsigned short* ldsB1 = &sB[w * 512 + 2048];

  f32x4 acc[4][4];
#pragma unroll
  for (int i = 0; i < 4; ++i)
#pragma unroll
    for (int j = 0; j < 4; ++j) acc[i][j] = (f32x4){0.f, 0.f, 0.f, 0.f};

  int fr = l & 15, k8 = l >> 4;

  for (int kb = 0; kb < KS_; ++kb) {
    const unsigned short* Ak = Wt + (size_t)kb * WSZ + (size_t)p0 * N_;
    const unsigned short* Bk = Gb + (size_t)kb * GSZ + (size_t)n0 * N_;
    const unsigned short* ga0 = Ak + (size_t)srow * N_ + scol;
    const unsigned short* ga1 = Ak + (size_t)(srow + 64) * N_ + scol;
    const unsigned short* gb0 = Bk + (size_t)srow * N_ + scol;
    const unsigned short* gb1 = Bk + (size_t)(srow + 64) * N_ + scol;

    for (int kt = 0; kt < N_ / BK; ++kt) {
      int ko = kt * BK;
      async16(ldsA0, ga0 + ko);
      async16(ldsA1, ga1 + ko);
      async16(ldsB0, gb0 + ko);
      async16(ldsB1, gb1 + ko);
      __syncthreads();

      bf16x8 af[4], bff[4];
#pragma unroll
      for (int mi = 0; mi < 4; ++mi)
        af[mi] = *reinterpret_cast<const bf16x8*>(&sA[(wr * 64 + mi * 16 + fr) * BK + k8 * 8]);
#pragma unroll
      for (int ni = 0; ni < 4; ++ni)
        bff[ni] = *reinterpret_cast<const bf16x8*>(&sB[(wc * 64 + ni * 16 + fr) * BK + k8 * 8]);

#pragma unroll
      for (int mi = 0; mi < 4; ++mi)
#pragma unroll
        for (int ni = 0; ni < 4; ++ni)
          acc[mi][ni] = __builtin_amdgcn_mfma_f32_16x16x32_bf16(af[mi], bff[ni], acc[mi][ni], 0, 0, 0);

      __syncthreads();
    }
  }

  // fused epilogue: out[p*N+n] = relu(C + bias[o] + x[p*N+n]); o = (p/12)%64
  int rbase = (l >> 4) * 4;
#pragma unroll
  for (int mi = 0; mi < 4; ++mi) {
#pragma unroll
    for (int ni = 0; ni < 4; ++ni) {
      f32x4 v = acc[mi][ni];
      int n = n0 + wc * 64 + ni * 16 + fr;
      int pb = p0 + wr * 64 + mi * 16 + rbase;
#pragma unroll
      for (int r = 0; r < 4; ++r) {
        int p = pb + r;
        int o = (p / T_) & (COUT - 1);
        size_t off = (size_t)p * N_ + n;
        float res = v[r] + bias[o] + xres[off];
        out[off] = fmaxf(res, 0.f);
      }
    }
  }
}

extern "C" void kernel_launch(void* const* d_in, const int* in_sizes, int n_in,
                              void* d_out, int out_size, void* d_ws, size_t ws_size,
                              hipStream_t stream) {
  const float* x     = (const float*)d_in[0];
  const float* g     = (const float*)d_in[1];
  const float* theta = (const float*)d_in[2];
  const float* bias  = (const float*)d_in[3];
  float* out = (float*)d_out;

  // workspace: Gb (bf16 bits) then Wt (bf16 bits) = 240 MiB total
  unsigned short* Gb = (unsigned short*)d_ws;
  unsigned short* Wt = Gb + KS_ * GSZ;

  // 1) cast G: 3*4096*4096 / 4 / 256 = 49152 blocks
  cast_g<<<49152, 256, 0, stream>>>((const float4*)g, (ushort4*)Gb);
  // 2) theta contraction: 96 (b,t) * 16 m-chunks
  stage1<<<96 * 16, 256, 0, stream>>>(x, theta, Wt);
  // 3) big GEMM + fused epilogue: 48*32 = 1536 blocks
  gemm_fused<<<1536, 256, 0, stream>>>(Wt, Gb, x, bias, out);
}